// Round 2
// baseline (779.064 us; speedup 1.0000x reference)
//
#include <hip/hip_runtime.h>
#include <hip/hip_bf16.h>
#include <cstdint>
#include <cstddef>

#define IN_DIM 512
#define OUT_DIM 256
#define BROWS 256          // rows per coarse bucket (bucket = row >> 8)
#define NBUCK_MAX 512      // supports M <= 131072 (col also packed in 17 bits)

typedef __bf16 bf16x8 __attribute__((ext_vector_type(8)));
typedef float f32x4 __attribute__((ext_vector_type(4)));
typedef unsigned short u16x8 __attribute__((ext_vector_type(8)));

__device__ __forceinline__ unsigned short f2bf(float f) {
    __bf16 h = (__bf16)f;
    return __builtin_bit_cast(unsigned short, h);
}
__device__ __forceinline__ float bf2f(unsigned short u) {
    unsigned int x = ((unsigned int)u) << 16;
    return __builtin_bit_cast(float, x);
}
__device__ __forceinline__ float selu(float x) {
    const float kScale = 1.0507009873554805f;
    const float kAlpha = 1.6732632423543772f;
    return (x > 0.f) ? kScale * x : kScale * kAlpha * (expf(x) - 1.f);
}

// ---------------- W convert + transpose: [512,256] f32 -> Wt [256,512] bf16 ----
__global__ void k_convW(const float* __restrict__ W, unsigned short* __restrict__ Wt) {
    int idx = blockIdx.x * 256 + threadIdx.x;   // 0..131071
    int n = idx & (OUT_DIM - 1);
    int k = idx >> 8;
    if (k < IN_DIM) Wt[n * IN_DIM + k] = f2bf(W[k * OUT_DIM + n]);
}

// ---------------- GEMM: xw = features @ W, full-N 128x256 tile ----------------
// 512 threads = 8 waves (2x4); each wave 4x4 of 16x16x32; A read ONCE.
__launch_bounds__(512, 2)
__global__ void k_gemm(const float* __restrict__ A, const unsigned short* __restrict__ Wt,
                       unsigned short* __restrict__ xw, int M) {
    __shared__ unsigned short lA[128 * 32];   // 8 KB
    __shared__ unsigned short lB[256 * 32];   // 16 KB
    const int t = threadIdx.x;
    const int wave = t >> 6, lane = t & 63;
    const int wr = wave >> 2, wc = wave & 3;   // 2 wave-rows x 4 wave-cols
    const int m0 = blockIdx.x * 128;
    const int mlo = lane & 15, kq = lane >> 4;

    f32x4 acc[4][4] = {};

    for (int k0 = 0; k0 < IN_DIM; k0 += 32) {
        // stage A: 128x32 f32 -> bf16 LDS; 1024 float4 chunks / 512 threads = 2
        #pragma unroll
        for (int p = 0; p < 2; ++p) {
            int idx = p * 512 + t;
            int r = idx >> 3, c4 = idx & 7;
            int gr = m0 + r; if (gr >= M) gr = M - 1;   // clamp
            const float4 v = *reinterpret_cast<const float4*>(&A[(size_t)gr * IN_DIM + k0 + c4 * 4]);
            ushort4 u;
            u.x = f2bf(v.x); u.y = f2bf(v.y); u.z = f2bf(v.z); u.w = f2bf(v.w);
            *reinterpret_cast<ushort4*>(&lA[r * 32 + c4 * 4]) = u;
        }
        // stage B: 256x32 bf16; 1024 x 16B chunks / 512 threads = 2
        #pragma unroll
        for (int p = 0; p < 2; ++p) {
            int idx = p * 512 + t;
            int n = idx >> 2, c8 = idx & 3;
            const uint4 v = *reinterpret_cast<const uint4*>(&Wt[(size_t)n * IN_DIM + k0 + c8 * 8]);
            *reinterpret_cast<uint4*>(&lB[n * 32 + c8 * 8]) = v;
        }
        __syncthreads();

        bf16x8 af[4], bfr[4];
        #pragma unroll
        for (int mt = 0; mt < 4; ++mt)
            af[mt] = *reinterpret_cast<const bf16x8*>(&lA[(wr * 64 + mt * 16 + mlo) * 32 + kq * 8]);
        #pragma unroll
        for (int nt = 0; nt < 4; ++nt)
            bfr[nt] = *reinterpret_cast<const bf16x8*>(&lB[(wc * 64 + nt * 16 + mlo) * 32 + kq * 8]);
        #pragma unroll
        for (int mt = 0; mt < 4; ++mt)
            #pragma unroll
            for (int nt = 0; nt < 4; ++nt)
                acc[mt][nt] = __builtin_amdgcn_mfma_f32_16x16x32_bf16(af[mt], bfr[nt], acc[mt][nt], 0, 0, 0);
        __syncthreads();
    }

    // store: C/D layout col=lane&15, row=(lane>>4)*4+i
    #pragma unroll
    for (int mt = 0; mt < 4; ++mt) {
        #pragma unroll
        for (int nt = 0; nt < 4; ++nt) {
            #pragma unroll
            for (int i = 0; i < 4; ++i) {
                int row = m0 + wr * 64 + mt * 16 + kq * 4 + i;
                int col = wc * 64 + nt * 16 + mlo;
                if (row < M) xw[(size_t)row * OUT_DIM + col] = f2bf(acc[mt][nt][i]);
            }
        }
    }
}

// ---------------- CSR build ---------------------------------------------------
__global__ void k_hist(const int* __restrict__ rows, int* __restrict__ counts, int E) {
    int i = (blockIdx.x * 256 + threadIdx.x) * 4;
    if (i + 4 <= E) {
        int4 r = *reinterpret_cast<const int4*>(&rows[i]);
        atomicAdd(&counts[r.x], 1);
        atomicAdd(&counts[r.y], 1);
        atomicAdd(&counts[r.z], 1);
        atomicAdd(&counts[r.w], 1);
    } else {
        for (int j = i; j < E; ++j) atomicAdd(&counts[rows[j]], 1);
    }
}

__global__ void k_scan1(const int* __restrict__ counts, int* __restrict__ rs,
                        int* __restrict__ bsum, int N) {
    int b = blockIdx.x, t = threadIdx.x;
    int base = b * 1024 + t * 4;
    int4 v = make_int4(0, 0, 0, 0);
    if (base + 4 <= N) v = *reinterpret_cast<const int4*>(&counts[base]);
    else {
        if (base + 0 < N) v.x = counts[base + 0];
        if (base + 1 < N) v.y = counts[base + 1];
        if (base + 2 < N) v.z = counts[base + 2];
        if (base + 3 < N) v.w = counts[base + 3];
    }
    int s0 = v.x, s1 = s0 + v.y, s2 = s1 + v.z, s3 = s2 + v.w;
    __shared__ int sh[256];
    sh[t] = s3; __syncthreads();
    for (int off = 1; off < 256; off <<= 1) {
        int x = (t >= off) ? sh[t - off] : 0;
        __syncthreads();
        sh[t] += x;
        __syncthreads();
    }
    int ex = sh[t] - s3;
    if (base + 0 < N) rs[base + 0] = ex;
    if (base + 1 < N) rs[base + 1] = ex + s0;
    if (base + 2 < N) rs[base + 2] = ex + s1;
    if (base + 3 < N) rs[base + 3] = ex + s2;
    if (t == 255) bsum[b] = sh[255];
}

__global__ void k_scan2(const int* __restrict__ bsum, int* __restrict__ boff, int nb) {
    int t = threadIdx.x;
    __shared__ int sh[256];
    int v = (t < nb) ? bsum[t] : 0;
    sh[t] = v; __syncthreads();
    for (int off = 1; off < 256; off <<= 1) {
        int x = (t >= off) ? sh[t - off] : 0;
        __syncthreads();
        sh[t] += x;
        __syncthreads();
    }
    if (t < nb) boff[t] = sh[t] - v;
}

__global__ void k_scan3(int* __restrict__ rs, int* __restrict__ cursor,
                        const int* __restrict__ boff, int N, int E) {
    int b = blockIdx.x, t = threadIdx.x;
    int base = b * 1024 + t * 4;
    int o = boff[b];
    #pragma unroll
    for (int j = 0; j < 4; ++j) {
        if (base + j < N) {
            int v = rs[base + j] + o;
            rs[base + j] = v;
            cursor[base + j] = v;
        }
    }
    if (b == 0 && t == 0) rs[N] = E;
}

// ---------------- OLD direct scatter (fallback only) --------------------------
__global__ void k_scatter(const int* __restrict__ rows, const int* __restrict__ cols,
                          const float* __restrict__ vals, int* __restrict__ cursor,
                          int2* __restrict__ ecv, int E) {
    int i = (blockIdx.x * 256 + threadIdx.x) * 4;
    if (i + 4 <= E) {
        int4 r = *reinterpret_cast<const int4*>(&rows[i]);
        int4 c = *reinterpret_cast<const int4*>(&cols[i]);
        float4 v = *reinterpret_cast<const float4*>(&vals[i]);
        int p0 = atomicAdd(&cursor[r.x], 1); ecv[p0] = make_int2(c.x, __float_as_int(v.x));
        int p1 = atomicAdd(&cursor[r.y], 1); ecv[p1] = make_int2(c.y, __float_as_int(v.y));
        int p2 = atomicAdd(&cursor[r.z], 1); ecv[p2] = make_int2(c.z, __float_as_int(v.z));
        int p3 = atomicAdd(&cursor[r.w], 1); ecv[p3] = make_int2(c.w, __float_as_int(v.w));
    } else {
        for (int j = i; j < E; ++j) {
            int p = atomicAdd(&cursor[rows[j]], 1);
            ecv[p] = make_int2(cols[j], __float_as_int(vals[j]));
        }
    }
}

// ---------------- bucket cursor init: bcursor[b] = rs[b*BROWS] ----------------
__global__ void k_binit(const int* __restrict__ rs, int* __restrict__ bcursor, int nbuck) {
    int b = blockIdx.x * 256 + threadIdx.x;
    if (b < nbuck) bcursor[b] = rs[b * BROWS];
}

// ---------------- Pass A: block-aggregated coarse binning ---------------------
__launch_bounds__(512)
__global__ void k_bin(const int* __restrict__ rows, const int* __restrict__ cols,
                      const float* __restrict__ vals, int* __restrict__ bcursor,
                      int2* __restrict__ binned, int E) {
    __shared__ int cnt[NBUCK_MAX];     // counts, then reused as running local cursor
    __shared__ int scn[NBUCK_MAX];     // scan workspace
    __shared__ int dlt[NBUCK_MAX];     // global_base - local_exclusive_base
    const int t = threadIdx.x;
    const int base = blockIdx.x * 8192;

    cnt[t] = 0;
    __syncthreads();

    // load 16 edges/thread, statically indexed (rule #20: no runtime-indexed regs)
    int er[16], ec[16];
    float ev[16];
    #pragma unroll
    for (int p = 0; p < 4; ++p) {
        const int i = base + p * 2048 + (t << 2);
        if (i + 4 <= E) {
            int4 r4 = *reinterpret_cast<const int4*>(&rows[i]);
            int4 c4 = *reinterpret_cast<const int4*>(&cols[i]);
            float4 v4 = *reinterpret_cast<const float4*>(&vals[i]);
            er[4*p+0] = r4.x; ec[4*p+0] = c4.x; ev[4*p+0] = v4.x;
            er[4*p+1] = r4.y; ec[4*p+1] = c4.y; ev[4*p+1] = v4.y;
            er[4*p+2] = r4.z; ec[4*p+2] = c4.z; ev[4*p+2] = v4.z;
            er[4*p+3] = r4.w; ec[4*p+3] = c4.w; ev[4*p+3] = v4.w;
        } else {
            #pragma unroll
            for (int j = 0; j < 4; ++j) {
                int idx = i + j;
                bool ok = idx < E;
                er[4*p+j] = ok ? rows[idx] : -1;
                ec[4*p+j] = ok ? cols[idx] : 0;
                ev[4*p+j] = ok ? vals[idx] : 0.f;
            }
        }
    }

    // count per bucket
    #pragma unroll
    for (int k = 0; k < 16; ++k)
        if (er[k] >= 0) atomicAdd(&cnt[er[k] >> 8], 1);
    __syncthreads();

    // block scan (Hillis-Steele over 512 slots, 512 threads)
    int v = cnt[t];
    scn[t] = v;
    __syncthreads();
    for (int off = 1; off < NBUCK_MAX; off <<= 1) {
        int x = (t >= off) ? scn[t - off] : 0;
        __syncthreads();
        scn[t] += x;
        __syncthreads();
    }
    int ex = scn[t] - v;   // exclusive prefix of this bucket within the block

    // reserve global chunk per non-empty bucket (one atomic per bucket per block)
    int d = 0;
    if (v > 0) d = atomicAdd(&bcursor[t], v) - ex;
    dlt[t] = d;
    cnt[t] = ex;           // reuse as running local cursor
    __syncthreads();

    // write records: global pos = dlt[bucket] + local_rank
    #pragma unroll
    for (int k = 0; k < 16; ++k) {
        if (er[k] >= 0) {
            int b = er[k] >> 8;
            int lp = atomicAdd(&cnt[b], 1);
            binned[(size_t)(dlt[b] + lp)] =
                make_int2(ec[k] | ((er[k] & 255) << 17), __float_as_int(ev[k]));
        }
    }
}

// ---------------- Pass B: per-bucket fine scatter into CSR order --------------
__launch_bounds__(256)
__global__ void k_fine(const int2* __restrict__ binned, const int* __restrict__ rs,
                       int2* __restrict__ ecv, int M) {
    __shared__ int lcur[BROWS];
    const int b = blockIdx.x, t = threadIdx.x;
    const int r0 = b * BROWS;
    const int rend = min(r0 + BROWS, M);
    if (r0 + t < rend) lcur[t] = rs[r0 + t];
    const int start = __builtin_amdgcn_readfirstlane(rs[r0]);
    const int end   = __builtin_amdgcn_readfirstlane(rs[rend]);
    __syncthreads();
    for (int i = start + t; i < end; i += 256) {
        int2 rec = binned[i];
        int r = rec.x >> 17;                        // row within bucket (bits 17..24)
        int pos = atomicAdd(&lcur[r], 1);
        ecv[pos] = make_int2(rec.x & 0x1FFFF, rec.y);
    }
}

// ---------------- CSR aggregation + fused epilogue ----------------------------
// One WAVE per node, HALF-WAVE-PAIR layout: lanes 0-31 process even edges,
// lanes 32-63 odd edges; each lane owns 8 dims (ushort8 = dwordx4 gather).
// One VMEM instruction covers 2 edges (1 KB); U=8 keeps 16 edges (8 KB)
// in flight per wave (2x the old scheme at half the VMEM instr/edge).
__launch_bounds__(256)
__global__ void k_agg(const unsigned short* __restrict__ xw,
                      const int2* __restrict__ ecv,
                      const int* __restrict__ rs,
                      const float* __restrict__ skipw,
                      const float* __restrict__ bias,
                      float* __restrict__ out, int M) {
    const int wave = threadIdx.x >> 6, lane = threadIdx.x & 63;
    const int node = blockIdx.x * 4 + wave;
    if (node >= M) return;
    const int s = __builtin_amdgcn_readfirstlane(rs[node]);
    const int e = __builtin_amdgcn_readfirstlane(rs[node + 1]);
    const int half = lane >> 5;          // which edge of the pair this lane handles
    const int hl = lane & 31;            // dim-group owner within half-wave
    const int d8 = hl * 8;               // this lane's 8 dims

    float acc[8] = {0.f, 0.f, 0.f, 0.f, 0.f, 0.f, 0.f, 0.f};

    constexpr int U = 8;                 // 8 pair-instructions = 16 edges in flight
    int p = s;
    for (; p + 2 * U <= e; p += 2 * U) {
        int   cs[U];
        float vs[U];
        #pragma unroll
        for (int u = 0; u < U; ++u) {
            int2 c = ecv[p + 2 * u + half];     // uniform per half-wave -> L1 broadcast
            cs[u] = c.x; vs[u] = __int_as_float(c.y);
        }
        u16x8 g[U];
        #pragma unroll
        for (int u = 0; u < U; ++u)
            g[u] = *reinterpret_cast<const u16x8*>(&xw[(size_t)cs[u] * OUT_DIM + d8]);
        #pragma unroll
        for (int u = 0; u < U; ++u) {
            #pragma unroll
            for (int j = 0; j < 8; ++j)
                acc[j] += vs[u] * bf2f(g[u][j]);
        }
    }
    // tail: 2 edges per step; pad wastes at most 1 gather per node
    for (; p < e; p += 2) {
        int idx = p + half;
        bool ok = idx < e;
        int2 c = ecv[ok ? idx : s];             // s < e here, safe
        float v = ok ? __int_as_float(c.y) : 0.f;
        u16x8 g = *reinterpret_cast<const u16x8*>(&xw[(size_t)c.x * OUT_DIM + d8]);
        #pragma unroll
        for (int j = 0; j < 8; ++j)
            acc[j] += v * bf2f(g[j]);
    }

    // combine the two half-wave partial sums (lane l <-> l+32 hold same dims)
    #pragma unroll
    for (int j = 0; j < 8; ++j)
        acc[j] += __shfl_xor(acc[j], 32);

    // epilogue: lane writes 4 of its 8 dims (half 0 -> low 4, half 1 -> high 4)
    float b0 = half ? acc[4] : acc[0];
    float b1 = half ? acc[5] : acc[1];
    float b2 = half ? acc[6] : acc[2];
    float b3 = half ? acc[7] : acc[3];
    const int db = d8 + half * 4;
    ushort4 xi = *reinterpret_cast<const ushort4*>(&xw[(size_t)node * OUT_DIM + db]);
    float4 sw = *reinterpret_cast<const float4*>(&skipw[db]);
    float4 bi = *reinterpret_cast<const float4*>(&bias[db]);
    float4 r;
    r.x = selu(b0 + bf2f(xi.x) * sw.x + bi.x);
    r.y = selu(b1 + bf2f(xi.y) * sw.y + bi.y);
    r.z = selu(b2 + bf2f(xi.z) * sw.z + bi.z);
    r.w = selu(b3 + bf2f(xi.w) * sw.w + bi.w);
    *reinterpret_cast<float4*>(&out[(size_t)node * OUT_DIM + db]) = r;
}

extern "C" void kernel_launch(void* const* d_in, const int* in_sizes, int n_in,
                              void* d_out, int out_size, void* d_ws, size_t ws_size,
                              hipStream_t stream) {
    const float* features = (const float*)d_in[0];
    const int*   adj_rows = (const int*)d_in[1];
    const int*   adj_cols = (const int*)d_in[2];
    const float* adj_vals = (const float*)d_in[3];
    const float* Wk       = (const float*)d_in[4];
    const float* bias     = (const float*)d_in[5];
    const float* skipw    = (const float*)d_in[6];
    float* out = (float*)d_out;

    const int M = in_sizes[0] / IN_DIM;     // 100000
    const int E = in_sizes[1];              // 3200000

    char* w = (char*)d_ws;
    size_t off = 0;
    auto carve = [&](size_t bytes) -> void* {
        void* p = w + off;
        off = (off + bytes + 255) & ~(size_t)255;
        return p;
    };
    unsigned short* xw = (unsigned short*)carve((size_t)M * OUT_DIM * 2);   // 51.2 MB
    unsigned short* Wt = (unsigned short*)carve((size_t)IN_DIM * OUT_DIM * 2);
    int*  counts = (int*)carve((size_t)M * 4);
    int*  rs     = (int*)carve((size_t)(M + 1) * 4);
    int*  cursor = (int*)carve((size_t)M * 4);
    int*  bsum   = (int*)carve(256 * 4);
    int*  boff   = (int*)carve(256 * 4);
    int*  bcur   = (int*)carve(NBUCK_MAX * 4);
    int2* ecv    = (int2*)carve((size_t)E * 8);                             // 25.6 MB
    int2* binned = (int2*)carve((size_t)E * 8);                             // 25.6 MB
    const int nbuck = (M + BROWS - 1) / BROWS;
    const bool use_binned = (off <= ws_size) && (nbuck <= NBUCK_MAX) && (M <= (1 << 17));

    hipMemsetAsync(counts, 0, (size_t)M * 4, stream);

    k_convW<<<(IN_DIM * OUT_DIM + 255) / 256, 256, 0, stream>>>(Wk, Wt);
    k_gemm<<<(M + 127) / 128, 512, 0, stream>>>(features, Wt, xw, M);

    k_hist<<<(E / 4 + 255) / 256, 256, 0, stream>>>(adj_rows, counts, E);
    int nb = (M + 1023) / 1024;
    k_scan1<<<nb, 256, 0, stream>>>(counts, rs, bsum, M);
    k_scan2<<<1, 256, 0, stream>>>(bsum, boff, nb);
    k_scan3<<<nb, 256, 0, stream>>>(rs, cursor, boff, M, E);

    if (use_binned) {
        k_binit<<<(nbuck + 255) / 256, 256, 0, stream>>>(rs, bcur, nbuck);
        k_bin<<<(E + 8191) / 8192, 512, 0, stream>>>(adj_rows, adj_cols, adj_vals, bcur, binned, E);
        k_fine<<<nbuck, 256, 0, stream>>>(binned, rs, ecv, M);
    } else {
        k_scatter<<<(E / 4 + 255) / 256, 256, 0, stream>>>(adj_rows, adj_cols, adj_vals, cursor, ecv, E);
    }

    k_agg<<<(M + 3) / 4, 256, 0, stream>>>(xw, ecv, rs, skipw, bias, out, M);
}

// Round 3
// 674.663 us; speedup vs baseline: 1.1547x; 1.1547x over previous
//
#include <hip/hip_runtime.h>
#include <hip/hip_bf16.h>
#include <cstdint>
#include <cstddef>

#define IN_DIM 512
#define OUT_DIM 256
#define BROWS 256          // rows per coarse bucket (bucket = row >> 8)
#define NBUCK_MAX 512      // supports M <= 131072 (col also packed in 17 bits)

typedef __bf16 bf16x8 __attribute__((ext_vector_type(8)));
typedef float f32x4 __attribute__((ext_vector_type(4)));

__device__ __forceinline__ unsigned short f2bf(float f) {
    __bf16 h = (__bf16)f;
    return __builtin_bit_cast(unsigned short, h);
}
__device__ __forceinline__ float bf2f(unsigned short u) {
    unsigned int x = ((unsigned int)u) << 16;
    return __builtin_bit_cast(float, x);
}
__device__ __forceinline__ float selu(float x) {
    const float kScale = 1.0507009873554805f;
    const float kAlpha = 1.6732632423543772f;
    return (x > 0.f) ? kScale * x : kScale * kAlpha * (expf(x) - 1.f);
}

// ---------------- W convert + transpose: [512,256] f32 -> Wt [256,512] bf16 ----
__global__ void k_convW(const float* __restrict__ W, unsigned short* __restrict__ Wt) {
    int idx = blockIdx.x * 256 + threadIdx.x;   // 0..131071
    int n = idx & (OUT_DIM - 1);
    int k = idx >> 8;
    if (k < IN_DIM) Wt[n * IN_DIM + k] = f2bf(W[k * OUT_DIM + n]);
}

// ---------------- GEMM: xw = features @ W -> per-row-scaled INT8 --------------
// 512 threads = 8 waves (2x4); each wave 4x4 of 16x16x32; A read ONCE.
// Epilogue: per-row absmax (16-lane butterfly + LDS atomicMax on float bits),
// quantize q = round(127*x/rowmax), store int8 + f32 scale per row.
__launch_bounds__(512, 2)
__global__ void k_gemm(const float* __restrict__ A, const unsigned short* __restrict__ Wt,
                       signed char* __restrict__ xq, float* __restrict__ scales, int M) {
    __shared__ unsigned short lA[128 * 32];   // 8 KB
    __shared__ unsigned short lB[256 * 32];   // 16 KB
    __shared__ float lrm[128];                // per-row absmax (float bits, >=0)
    const int t = threadIdx.x;
    const int wave = t >> 6, lane = t & 63;
    const int wr = wave >> 2, wc = wave & 3;   // 2 wave-rows x 4 wave-cols
    const int m0 = blockIdx.x * 128;
    const int mlo = lane & 15, kq = lane >> 4;

    if (t < 128) lrm[t] = 0.f;                // covered by first loop barrier

    f32x4 acc[4][4] = {};

    for (int k0 = 0; k0 < IN_DIM; k0 += 32) {
        // stage A: 128x32 f32 -> bf16 LDS; 1024 float4 chunks / 512 threads = 2
        #pragma unroll
        for (int p = 0; p < 2; ++p) {
            int idx = p * 512 + t;
            int r = idx >> 3, c4 = idx & 7;
            int gr = m0 + r; if (gr >= M) gr = M - 1;   // clamp
            const float4 v = *reinterpret_cast<const float4*>(&A[(size_t)gr * IN_DIM + k0 + c4 * 4]);
            ushort4 u;
            u.x = f2bf(v.x); u.y = f2bf(v.y); u.z = f2bf(v.z); u.w = f2bf(v.w);
            *reinterpret_cast<ushort4*>(&lA[r * 32 + c4 * 4]) = u;
        }
        // stage B: 256x32 bf16; 1024 x 16B chunks / 512 threads = 2
        #pragma unroll
        for (int p = 0; p < 2; ++p) {
            int idx = p * 512 + t;
            int n = idx >> 2, c8 = idx & 3;
            const uint4 v = *reinterpret_cast<const uint4*>(&Wt[(size_t)n * IN_DIM + k0 + c8 * 8]);
            *reinterpret_cast<uint4*>(&lB[n * 32 + c8 * 8]) = v;
        }
        __syncthreads();

        bf16x8 af[4], bfr[4];
        #pragma unroll
        for (int mt = 0; mt < 4; ++mt)
            af[mt] = *reinterpret_cast<const bf16x8*>(&lA[(wr * 64 + mt * 16 + mlo) * 32 + kq * 8]);
        #pragma unroll
        for (int nt = 0; nt < 4; ++nt)
            bfr[nt] = *reinterpret_cast<const bf16x8*>(&lB[(wc * 64 + nt * 16 + mlo) * 32 + kq * 8]);
        #pragma unroll
        for (int mt = 0; mt < 4; ++mt)
            #pragma unroll
            for (int nt = 0; nt < 4; ++nt)
                acc[mt][nt] = __builtin_amdgcn_mfma_f32_16x16x32_bf16(af[mt], bfr[nt], acc[mt][nt], 0, 0, 0);
        __syncthreads();
    }

    // ---- per-row absmax: C/D layout col=wc*64+nt*16+mlo, row=wr*64+mt*16+kq*4+i
    #pragma unroll
    for (int mt = 0; mt < 4; ++mt) {
        #pragma unroll
        for (int i = 0; i < 4; ++i) {
            float m = fmaxf(fmaxf(fabsf(acc[mt][0][i]), fabsf(acc[mt][1][i])),
                            fmaxf(fabsf(acc[mt][2][i]), fabsf(acc[mt][3][i])));
            m = fmaxf(m, __shfl_xor(m, 1));
            m = fmaxf(m, __shfl_xor(m, 2));
            m = fmaxf(m, __shfl_xor(m, 4));
            m = fmaxf(m, __shfl_xor(m, 8));
            if (mlo == 0)
                atomicMax(reinterpret_cast<int*>(&lrm[wr * 64 + mt * 16 + kq * 4 + i]),
                          __float_as_int(m));   // all values >= 0: float bits monotone
        }
    }
    __syncthreads();

    // ---- quantize + store int8
    #pragma unroll
    for (int mt = 0; mt < 4; ++mt) {
        #pragma unroll
        for (int i = 0; i < 4; ++i) {
            const int rl = wr * 64 + mt * 16 + kq * 4 + i;
            const int row = m0 + rl;
            const float rm = lrm[rl];
            const float inv = (rm > 0.f) ? (127.f / rm) : 0.f;
            if (row < M) {
                #pragma unroll
                for (int nt = 0; nt < 4; ++nt) {
                    int q = (int)rintf(acc[mt][nt][i] * inv);   // |q| <= 127 by construction
                    xq[(size_t)row * OUT_DIM + wc * 64 + nt * 16 + mlo] = (signed char)q;
                }
            }
        }
    }
    if (t < 128) {
        int row = m0 + t;
        if (row < M) scales[row] = lrm[t] * (1.f / 127.f);
    }
}

// ---------------- CSR build ---------------------------------------------------
__global__ void k_hist(const int* __restrict__ rows, int* __restrict__ counts, int E) {
    int i = (blockIdx.x * 256 + threadIdx.x) * 4;
    if (i + 4 <= E) {
        int4 r = *reinterpret_cast<const int4*>(&rows[i]);
        atomicAdd(&counts[r.x], 1);
        atomicAdd(&counts[r.y], 1);
        atomicAdd(&counts[r.z], 1);
        atomicAdd(&counts[r.w], 1);
    } else {
        for (int j = i; j < E; ++j) atomicAdd(&counts[rows[j]], 1);
    }
}

__global__ void k_scan1(const int* __restrict__ counts, int* __restrict__ rs,
                        int* __restrict__ bsum, int N) {
    int b = blockIdx.x, t = threadIdx.x;
    int base = b * 1024 + t * 4;
    int4 v = make_int4(0, 0, 0, 0);
    if (base + 4 <= N) v = *reinterpret_cast<const int4*>(&counts[base]);
    else {
        if (base + 0 < N) v.x = counts[base + 0];
        if (base + 1 < N) v.y = counts[base + 1];
        if (base + 2 < N) v.z = counts[base + 2];
        if (base + 3 < N) v.w = counts[base + 3];
    }
    int s0 = v.x, s1 = s0 + v.y, s2 = s1 + v.z, s3 = s2 + v.w;
    __shared__ int sh[256];
    sh[t] = s3; __syncthreads();
    for (int off = 1; off < 256; off <<= 1) {
        int x = (t >= off) ? sh[t - off] : 0;
        __syncthreads();
        sh[t] += x;
        __syncthreads();
    }
    int ex = sh[t] - s3;
    if (base + 0 < N) rs[base + 0] = ex;
    if (base + 1 < N) rs[base + 1] = ex + s0;
    if (base + 2 < N) rs[base + 2] = ex + s1;
    if (base + 3 < N) rs[base + 3] = ex + s2;
    if (t == 255) bsum[b] = sh[255];
}

__global__ void k_scan2(const int* __restrict__ bsum, int* __restrict__ boff, int nb) {
    int t = threadIdx.x;
    __shared__ int sh[256];
    int v = (t < nb) ? bsum[t] : 0;
    sh[t] = v; __syncthreads();
    for (int off = 1; off < 256; off <<= 1) {
        int x = (t >= off) ? sh[t - off] : 0;
        __syncthreads();
        sh[t] += x;
        __syncthreads();
    }
    if (t < nb) boff[t] = sh[t] - v;
}

__global__ void k_scan3(int* __restrict__ rs, int* __restrict__ cursor,
                        const int* __restrict__ boff, int N, int E) {
    int b = blockIdx.x, t = threadIdx.x;
    int base = b * 1024 + t * 4;
    int o = boff[b];
    #pragma unroll
    for (int j = 0; j < 4; ++j) {
        if (base + j < N) {
            int v = rs[base + j] + o;
            rs[base + j] = v;
            cursor[base + j] = v;
        }
    }
    if (b == 0 && t == 0) rs[N] = E;
}

// ---------------- OLD direct scatter (fallback only; folds col scale) ---------
__global__ void k_scatter(const int* __restrict__ rows, const int* __restrict__ cols,
                          const float* __restrict__ vals, const float* __restrict__ scales,
                          int* __restrict__ cursor, int2* __restrict__ ecv, int E) {
    int i = (blockIdx.x * 256 + threadIdx.x) * 4;
    if (i + 4 <= E) {
        int4 r = *reinterpret_cast<const int4*>(&rows[i]);
        int4 c = *reinterpret_cast<const int4*>(&cols[i]);
        float4 v = *reinterpret_cast<const float4*>(&vals[i]);
        int p0 = atomicAdd(&cursor[r.x], 1); ecv[p0] = make_int2(c.x, __float_as_int(v.x * scales[c.x]));
        int p1 = atomicAdd(&cursor[r.y], 1); ecv[p1] = make_int2(c.y, __float_as_int(v.y * scales[c.y]));
        int p2 = atomicAdd(&cursor[r.z], 1); ecv[p2] = make_int2(c.z, __float_as_int(v.z * scales[c.z]));
        int p3 = atomicAdd(&cursor[r.w], 1); ecv[p3] = make_int2(c.w, __float_as_int(v.w * scales[c.w]));
    } else {
        for (int j = i; j < E; ++j) {
            int p = atomicAdd(&cursor[rows[j]], 1);
            ecv[p] = make_int2(cols[j], __float_as_int(vals[j] * scales[cols[j]]));
        }
    }
}

// ---------------- bucket cursor init: bcursor[b] = rs[b*BROWS] ----------------
__global__ void k_binit(const int* __restrict__ rs, int* __restrict__ bcursor, int nbuck) {
    int b = blockIdx.x * 256 + threadIdx.x;
    if (b < nbuck) bcursor[b] = rs[b * BROWS];
}

// ---------------- Pass A: block-aggregated coarse binning ---------------------
__launch_bounds__(512)
__global__ void k_bin(const int* __restrict__ rows, const int* __restrict__ cols,
                      const float* __restrict__ vals, int* __restrict__ bcursor,
                      int2* __restrict__ binned, int E) {
    __shared__ int cnt[NBUCK_MAX];     // counts, then reused as running local cursor
    __shared__ int scn[NBUCK_MAX];     // scan workspace
    __shared__ int dlt[NBUCK_MAX];     // global_base - local_exclusive_base
    const int t = threadIdx.x;
    const int base = blockIdx.x * 8192;

    cnt[t] = 0;
    __syncthreads();

    // load 16 edges/thread, statically indexed (rule #20: no runtime-indexed regs)
    int er[16], ec[16];
    float ev[16];
    #pragma unroll
    for (int p = 0; p < 4; ++p) {
        const int i = base + p * 2048 + (t << 2);
        if (i + 4 <= E) {
            int4 r4 = *reinterpret_cast<const int4*>(&rows[i]);
            int4 c4 = *reinterpret_cast<const int4*>(&cols[i]);
            float4 v4 = *reinterpret_cast<const float4*>(&vals[i]);
            er[4*p+0] = r4.x; ec[4*p+0] = c4.x; ev[4*p+0] = v4.x;
            er[4*p+1] = r4.y; ec[4*p+1] = c4.y; ev[4*p+1] = v4.y;
            er[4*p+2] = r4.z; ec[4*p+2] = c4.z; ev[4*p+2] = v4.z;
            er[4*p+3] = r4.w; ec[4*p+3] = c4.w; ev[4*p+3] = v4.w;
        } else {
            #pragma unroll
            for (int j = 0; j < 4; ++j) {
                int idx = i + j;
                bool ok = idx < E;
                er[4*p+j] = ok ? rows[idx] : -1;
                ec[4*p+j] = ok ? cols[idx] : 0;
                ev[4*p+j] = ok ? vals[idx] : 0.f;
            }
        }
    }

    // count per bucket
    #pragma unroll
    for (int k = 0; k < 16; ++k)
        if (er[k] >= 0) atomicAdd(&cnt[er[k] >> 8], 1);
    __syncthreads();

    // block scan (Hillis-Steele over 512 slots, 512 threads)
    int v = cnt[t];
    scn[t] = v;
    __syncthreads();
    for (int off = 1; off < NBUCK_MAX; off <<= 1) {
        int x = (t >= off) ? scn[t - off] : 0;
        __syncthreads();
        scn[t] += x;
        __syncthreads();
    }
    int ex = scn[t] - v;   // exclusive prefix of this bucket within the block

    // reserve global chunk per non-empty bucket (one atomic per bucket per block)
    int d = 0;
    if (v > 0) d = atomicAdd(&bcursor[t], v) - ex;
    dlt[t] = d;
    cnt[t] = ex;           // reuse as running local cursor
    __syncthreads();

    // write records: global pos = dlt[bucket] + local_rank
    #pragma unroll
    for (int k = 0; k < 16; ++k) {
        if (er[k] >= 0) {
            int b = er[k] >> 8;
            int lp = atomicAdd(&cnt[b], 1);
            binned[(size_t)(dlt[b] + lp)] =
                make_int2(ec[k] | ((er[k] & 255) << 17), __float_as_int(ev[k]));
        }
    }
}

// ---------------- Pass B: per-bucket fine scatter into CSR order --------------
// Folds the per-col dequant scale into the stored edge value:
// ecv = (col, val * scales[col])  -> k_agg needs zero scale loads.
__launch_bounds__(256)
__global__ void k_fine(const int2* __restrict__ binned, const int* __restrict__ rs,
                       const float* __restrict__ scales, int2* __restrict__ ecv, int M) {
    __shared__ int lcur[BROWS];
    const int b = blockIdx.x, t = threadIdx.x;
    const int r0 = b * BROWS;
    const int rend = min(r0 + BROWS, M);
    if (r0 + t < rend) lcur[t] = rs[r0 + t];
    const int start = __builtin_amdgcn_readfirstlane(rs[r0]);
    const int end   = __builtin_amdgcn_readfirstlane(rs[rend]);
    __syncthreads();
    for (int i = start + t; i < end; i += 256) {
        int2 rec = binned[i];
        int r = rec.x >> 17;                        // row within bucket (bits 17..24)
        int col = rec.x & 0x1FFFF;
        int pos = atomicAdd(&lcur[r], 1);
        ecv[pos] = make_int2(col, __float_as_int(__int_as_float(rec.y) * scales[col]));
    }
}

// ---------------- CSR aggregation + fused epilogue (INT8 gather) --------------
// one WAVE per node; lane l owns dims 4l..4l+3: ONE dword load per edge per
// lane (256B/wave/edge, half the bf16 bytes). ecv.y already = val*scale[col].
__launch_bounds__(256)
__global__ void k_agg(const signed char* __restrict__ xq,
                      const float* __restrict__ scales,
                      const int2* __restrict__ ecv,
                      const int* __restrict__ rs,
                      const float* __restrict__ skipw,
                      const float* __restrict__ bias,
                      float* __restrict__ out, int M) {
    const int wave = threadIdx.x >> 6, lane = threadIdx.x & 63;
    const int node = blockIdx.x * 4 + wave;
    if (node >= M) return;
    const int s = __builtin_amdgcn_readfirstlane(rs[node]);
    const int e = __builtin_amdgcn_readfirstlane(rs[node + 1]);
    const int d4 = lane * 4;

    float a0 = 0.f, a1 = 0.f, a2 = 0.f, a3 = 0.f;
    int p = s;
    constexpr int U = 8;
    for (; p + U <= e; p += U) {
        int   cs[U];
        float vs[U];
        #pragma unroll
        for (int u = 0; u < U; ++u) {
            int2 c = ecv[p + u];           // wave-uniform address -> L1 broadcast
            cs[u] = c.x; vs[u] = __int_as_float(c.y);
        }
        int g[U];
        #pragma unroll
        for (int u = 0; u < U; ++u)
            g[u] = *reinterpret_cast<const int*>(&xq[(size_t)cs[u] * OUT_DIM + d4]);
        #pragma unroll
        for (int u = 0; u < U; ++u) {
            a0 += vs[u] * (float)(signed char)(g[u]);
            a1 += vs[u] * (float)(signed char)(g[u] >> 8);
            a2 += vs[u] * (float)(signed char)(g[u] >> 16);
            a3 += vs[u] * (float)(g[u] >> 24);
        }
    }
    for (; p < e; ++p) {
        int2 c = ecv[p];
        float v = __int_as_float(c.y);
        int g = *reinterpret_cast<const int*>(&xq[(size_t)c.x * OUT_DIM + d4]);
        a0 += v * (float)(signed char)(g);
        a1 += v * (float)(signed char)(g >> 8);
        a2 += v * (float)(signed char)(g >> 16);
        a3 += v * (float)(g >> 24);
    }

    // skip path: own row int8 + own scale
    int w = *reinterpret_cast<const int*>(&xq[(size_t)node * OUT_DIM + d4]);
    float sc = scales[node];
    float x0 = (float)(signed char)(w)        * sc;
    float x1 = (float)(signed char)(w >> 8)   * sc;
    float x2 = (float)(signed char)(w >> 16)  * sc;
    float x3 = (float)(w >> 24)               * sc;

    float4 sw = *reinterpret_cast<const float4*>(&skipw[d4]);
    float4 bi = *reinterpret_cast<const float4*>(&bias[d4]);
    float4 r;
    r.x = selu(a0 + x0 * sw.x + bi.x);
    r.y = selu(a1 + x1 * sw.y + bi.y);
    r.z = selu(a2 + x2 * sw.z + bi.z);
    r.w = selu(a3 + x3 * sw.w + bi.w);
    *reinterpret_cast<float4*>(&out[(size_t)node * OUT_DIM + d4]) = r;
}

extern "C" void kernel_launch(void* const* d_in, const int* in_sizes, int n_in,
                              void* d_out, int out_size, void* d_ws, size_t ws_size,
                              hipStream_t stream) {
    const float* features = (const float*)d_in[0];
    const int*   adj_rows = (const int*)d_in[1];
    const int*   adj_cols = (const int*)d_in[2];
    const float* adj_vals = (const float*)d_in[3];
    const float* Wk       = (const float*)d_in[4];
    const float* bias     = (const float*)d_in[5];
    const float* skipw    = (const float*)d_in[6];
    float* out = (float*)d_out;

    const int M = in_sizes[0] / IN_DIM;     // 100000
    const int E = in_sizes[1];              // 3200000

    char* w = (char*)d_ws;
    size_t off = 0;
    auto carve = [&](size_t bytes) -> void* {
        void* p = w + off;
        off = (off + bytes + 255) & ~(size_t)255;
        return p;
    };
    signed char* xq = (signed char*)carve((size_t)M * OUT_DIM);             // 25.6 MB
    float* scales   = (float*)carve((size_t)M * 4);                         // 0.4 MB
    unsigned short* Wt = (unsigned short*)carve((size_t)IN_DIM * OUT_DIM * 2);
    int*  counts = (int*)carve((size_t)M * 4);
    int*  rs     = (int*)carve((size_t)(M + 1) * 4);
    int*  cursor = (int*)carve((size_t)M * 4);
    int*  bsum   = (int*)carve(256 * 4);
    int*  boff   = (int*)carve(256 * 4);
    int*  bcur   = (int*)carve(NBUCK_MAX * 4);
    int2* ecv    = (int2*)carve((size_t)E * 8);                             // 25.6 MB
    int2* binned = (int2*)carve((size_t)E * 8);                             // 25.6 MB
    const int nbuck = (M + BROWS - 1) / BROWS;
    const bool use_binned = (off <= ws_size) && (nbuck <= NBUCK_MAX) && (M <= (1 << 17));

    hipMemsetAsync(counts, 0, (size_t)M * 4, stream);

    k_convW<<<(IN_DIM * OUT_DIM + 255) / 256, 256, 0, stream>>>(Wk, Wt);
    k_gemm<<<(M + 127) / 128, 512, 0, stream>>>(features, Wt, xq, scales, M);

    k_hist<<<(E / 4 + 255) / 256, 256, 0, stream>>>(adj_rows, counts, E);
    int nb = (M + 1023) / 1024;
    k_scan1<<<nb, 256, 0, stream>>>(counts, rs, bsum, M);
    k_scan2<<<1, 256, 0, stream>>>(bsum, boff, nb);
    k_scan3<<<nb, 256, 0, stream>>>(rs, cursor, boff, M, E);

    if (use_binned) {
        k_binit<<<(nbuck + 255) / 256, 256, 0, stream>>>(rs, bcur, nbuck);
        k_bin<<<(E + 8191) / 8192, 512, 0, stream>>>(adj_rows, adj_cols, adj_vals, bcur, binned, E);
        k_fine<<<nbuck, 256, 0, stream>>>(binned, rs, scales, ecv, M);
    } else {
        k_scatter<<<(E / 4 + 255) / 256, 256, 0, stream>>>(adj_rows, adj_cols, adj_vals, scales, cursor, ecv, E);
    }

    k_agg<<<(M + 3) / 4, 256, 0, stream>>>(xq, scales, ecv, rs, skipw, bias, out, M);
}

// Round 4
// 566.955 us; speedup vs baseline: 1.3741x; 1.1900x over previous
//
#include <hip/hip_runtime.h>
#include <hip/hip_bf16.h>
#include <cstdint>
#include <cstddef>

#define IN_DIM 512
#define OUT_DIM 256
#define BROWS 256          // rows per coarse bucket (bucket = row >> 8)
#define NBUCK_MAX 512      // supports M <= 131072 (col also packed in 17 bits)

typedef __bf16 bf16x8 __attribute__((ext_vector_type(8)));
typedef float f32x4 __attribute__((ext_vector_type(4)));

__device__ __forceinline__ unsigned short f2bf(float f) {
    __bf16 h = (__bf16)f;
    return __builtin_bit_cast(unsigned short, h);
}
__device__ __forceinline__ float bf2f(unsigned short u) {
    unsigned int x = ((unsigned int)u) << 16;
    return __builtin_bit_cast(float, x);
}
__device__ __forceinline__ float selu(float x) {
    const float kScale = 1.0507009873554805f;
    const float kAlpha = 1.6732632423543772f;
    return (x > 0.f) ? kScale * x : kScale * kAlpha * (expf(x) - 1.f);
}

// ---------------- W convert + transpose: [512,256] f32 -> Wt [256,512] bf16 ----
__global__ void k_convW(const float* __restrict__ W, unsigned short* __restrict__ Wt) {
    int idx = blockIdx.x * 256 + threadIdx.x;   // 0..131071
    int n = idx & (OUT_DIM - 1);
    int k = idx >> 8;
    if (k < IN_DIM) Wt[n * IN_DIM + k] = f2bf(W[k * OUT_DIM + n]);
}

// ---------------- GEMM: xw = features @ W -> per-row-scaled INT8 --------------
__launch_bounds__(512, 2)
__global__ void k_gemm(const float* __restrict__ A, const unsigned short* __restrict__ Wt,
                       signed char* __restrict__ xq, float* __restrict__ scales, int M) {
    __shared__ unsigned short lA[128 * 32];   // 8 KB
    __shared__ unsigned short lB[256 * 32];   // 16 KB
    __shared__ float lrm[128];                // per-row absmax (float bits, >=0)
    const int t = threadIdx.x;
    const int wave = t >> 6, lane = t & 63;
    const int wr = wave >> 2, wc = wave & 3;   // 2 wave-rows x 4 wave-cols
    const int m0 = blockIdx.x * 128;
    const int mlo = lane & 15, kq = lane >> 4;

    if (t < 128) lrm[t] = 0.f;                // covered by first loop barrier

    f32x4 acc[4][4] = {};

    for (int k0 = 0; k0 < IN_DIM; k0 += 32) {
        // stage A: 128x32 f32 -> bf16 LDS; 1024 float4 chunks / 512 threads = 2
        #pragma unroll
        for (int p = 0; p < 2; ++p) {
            int idx = p * 512 + t;
            int r = idx >> 3, c4 = idx & 7;
            int gr = m0 + r; if (gr >= M) gr = M - 1;   // clamp
            const float4 v = *reinterpret_cast<const float4*>(&A[(size_t)gr * IN_DIM + k0 + c4 * 4]);
            ushort4 u;
            u.x = f2bf(v.x); u.y = f2bf(v.y); u.z = f2bf(v.z); u.w = f2bf(v.w);
            *reinterpret_cast<ushort4*>(&lA[r * 32 + c4 * 4]) = u;
        }
        // stage B: 256x32 bf16; 1024 x 16B chunks / 512 threads = 2
        #pragma unroll
        for (int p = 0; p < 2; ++p) {
            int idx = p * 512 + t;
            int n = idx >> 2, c8 = idx & 3;
            const uint4 v = *reinterpret_cast<const uint4*>(&Wt[(size_t)n * IN_DIM + k0 + c8 * 8]);
            *reinterpret_cast<uint4*>(&lB[n * 32 + c8 * 8]) = v;
        }
        __syncthreads();

        bf16x8 af[4], bfr[4];
        #pragma unroll
        for (int mt = 0; mt < 4; ++mt)
            af[mt] = *reinterpret_cast<const bf16x8*>(&lA[(wr * 64 + mt * 16 + mlo) * 32 + kq * 8]);
        #pragma unroll
        for (int nt = 0; nt < 4; ++nt)
            bfr[nt] = *reinterpret_cast<const bf16x8*>(&lB[(wc * 64 + nt * 16 + mlo) * 32 + kq * 8]);
        #pragma unroll
        for (int mt = 0; mt < 4; ++mt)
            #pragma unroll
            for (int nt = 0; nt < 4; ++nt)
                acc[mt][nt] = __builtin_amdgcn_mfma_f32_16x16x32_bf16(af[mt], bfr[nt], acc[mt][nt], 0, 0, 0);
        __syncthreads();
    }

    // ---- per-row absmax: C/D layout col=wc*64+nt*16+mlo, row=wr*64+mt*16+kq*4+i
    #pragma unroll
    for (int mt = 0; mt < 4; ++mt) {
        #pragma unroll
        for (int i = 0; i < 4; ++i) {
            float m = fmaxf(fmaxf(fabsf(acc[mt][0][i]), fabsf(acc[mt][1][i])),
                            fmaxf(fabsf(acc[mt][2][i]), fabsf(acc[mt][3][i])));
            m = fmaxf(m, __shfl_xor(m, 1));
            m = fmaxf(m, __shfl_xor(m, 2));
            m = fmaxf(m, __shfl_xor(m, 4));
            m = fmaxf(m, __shfl_xor(m, 8));
            if (mlo == 0)
                atomicMax(reinterpret_cast<int*>(&lrm[wr * 64 + mt * 16 + kq * 4 + i]),
                          __float_as_int(m));   // all values >= 0: float bits monotone
        }
    }
    __syncthreads();

    // ---- quantize + store int8
    #pragma unroll
    for (int mt = 0; mt < 4; ++mt) {
        #pragma unroll
        for (int i = 0; i < 4; ++i) {
            const int rl = wr * 64 + mt * 16 + kq * 4 + i;
            const int row = m0 + rl;
            const float rm = lrm[rl];
            const float inv = (rm > 0.f) ? (127.f / rm) : 0.f;
            if (row < M) {
                #pragma unroll
                for (int nt = 0; nt < 4; ++nt) {
                    int q = (int)rintf(acc[mt][nt][i] * inv);   // |q| <= 127 by construction
                    xq[(size_t)row * OUT_DIM + wc * 64 + nt * 16 + mlo] = (signed char)q;
                }
            }
        }
    }
    if (t < 128) {
        int row = m0 + t;
        if (row < M) scales[row] = lrm[t] * (1.f / 127.f);
    }
}

// ---------------- bucket-level histogram (replaces row-level k_hist) ----------
// LDS-aggregated: per block 512-counter LDS hist, then <=NBUCK global atomics.
// 3.2M edges -> ~153K global atomics instead of 3.2M.
__launch_bounds__(512)
__global__ void k_bhist(const int* __restrict__ rows, int* __restrict__ bcnt, int E) {
    __shared__ int cnt[NBUCK_MAX];
    const int t = threadIdx.x;
    const int base = blockIdx.x * 8192;
    cnt[t] = 0;
    __syncthreads();
    #pragma unroll
    for (int p = 0; p < 4; ++p) {
        const int i = base + p * 2048 + (t << 2);
        if (i + 4 <= E) {
            int4 r4 = *reinterpret_cast<const int4*>(&rows[i]);
            atomicAdd(&cnt[r4.x >> 8], 1);
            atomicAdd(&cnt[r4.y >> 8], 1);
            atomicAdd(&cnt[r4.z >> 8], 1);
            atomicAdd(&cnt[r4.w >> 8], 1);
        } else if (i < E) {
            for (int j = i; j < E && j < i + 4; ++j) atomicAdd(&cnt[rows[j] >> 8], 1);
        }
    }
    __syncthreads();
    if (cnt[t] > 0) atomicAdd(&bcnt[t], cnt[t]);
}

// ---------------- bucket scan: bbase = exclusive-scan(bcnt); bcursor = bbase --
__launch_bounds__(NBUCK_MAX)
__global__ void k_bscan(const int* __restrict__ bcnt, int* __restrict__ bbase,
                        int* __restrict__ bcursor, int nbuck, int E) {
    const int t = threadIdx.x;
    __shared__ int sh[NBUCK_MAX];
    int v = (t < nbuck) ? bcnt[t] : 0;
    sh[t] = v;
    __syncthreads();
    for (int off = 1; off < NBUCK_MAX; off <<= 1) {
        int x = (t >= off) ? sh[t - off] : 0;
        __syncthreads();
        sh[t] += x;
        __syncthreads();
    }
    int ex = sh[t] - v;          // for t >= nbuck this equals E (v=0)
    bbase[t] = ex;
    bcursor[t] = ex;
    if (t == 0) bbase[NBUCK_MAX] = E;
}

// ---------------- Pass A: block-aggregated coarse binning ---------------------
__launch_bounds__(512)
__global__ void k_bin(const int* __restrict__ rows, const int* __restrict__ cols,
                      const float* __restrict__ vals, int* __restrict__ bcursor,
                      int2* __restrict__ binned, int E) {
    __shared__ int cnt[NBUCK_MAX];     // counts, then reused as running local cursor
    __shared__ int scn[NBUCK_MAX];     // scan workspace
    __shared__ int dlt[NBUCK_MAX];     // global_base - local_exclusive_base
    const int t = threadIdx.x;
    const int base = blockIdx.x * 8192;

    cnt[t] = 0;
    __syncthreads();

    // load 16 edges/thread, statically indexed (rule #20: no runtime-indexed regs)
    int er[16], ec[16];
    float ev[16];
    #pragma unroll
    for (int p = 0; p < 4; ++p) {
        const int i = base + p * 2048 + (t << 2);
        if (i + 4 <= E) {
            int4 r4 = *reinterpret_cast<const int4*>(&rows[i]);
            int4 c4 = *reinterpret_cast<const int4*>(&cols[i]);
            float4 v4 = *reinterpret_cast<const float4*>(&vals[i]);
            er[4*p+0] = r4.x; ec[4*p+0] = c4.x; ev[4*p+0] = v4.x;
            er[4*p+1] = r4.y; ec[4*p+1] = c4.y; ev[4*p+1] = v4.y;
            er[4*p+2] = r4.z; ec[4*p+2] = c4.z; ev[4*p+2] = v4.z;
            er[4*p+3] = r4.w; ec[4*p+3] = c4.w; ev[4*p+3] = v4.w;
        } else {
            #pragma unroll
            for (int j = 0; j < 4; ++j) {
                int idx = i + j;
                bool ok = idx < E;
                er[4*p+j] = ok ? rows[idx] : -1;
                ec[4*p+j] = ok ? cols[idx] : 0;
                ev[4*p+j] = ok ? vals[idx] : 0.f;
            }
        }
    }

    // count per bucket
    #pragma unroll
    for (int k = 0; k < 16; ++k)
        if (er[k] >= 0) atomicAdd(&cnt[er[k] >> 8], 1);
    __syncthreads();

    // block scan (Hillis-Steele over 512 slots, 512 threads)
    int v = cnt[t];
    scn[t] = v;
    __syncthreads();
    for (int off = 1; off < NBUCK_MAX; off <<= 1) {
        int x = (t >= off) ? scn[t - off] : 0;
        __syncthreads();
        scn[t] += x;
        __syncthreads();
    }
    int ex = scn[t] - v;   // exclusive prefix of this bucket within the block

    // reserve global chunk per non-empty bucket (one atomic per bucket per block)
    int d = 0;
    if (v > 0) d = atomicAdd(&bcursor[t], v) - ex;
    dlt[t] = d;
    cnt[t] = ex;           // reuse as running local cursor
    __syncthreads();

    // write records: global pos = dlt[bucket] + local_rank
    #pragma unroll
    for (int k = 0; k < 16; ++k) {
        if (er[k] >= 0) {
            int b = er[k] >> 8;
            int lp = atomicAdd(&cnt[b], 1);
            binned[(size_t)(dlt[b] + lp)] =
                make_int2(ec[k] | ((er[k] & 255) << 17), __float_as_int(ev[k]));
        }
    }
}

// ---------------- Pass B: per-bucket fine scatter + rs derivation -------------
// Sweep 1 counts rows in LDS, block-scan -> row offsets rs (replaces the global
// row histogram + scans entirely). Sweep 2 re-reads the bucket slice (L2-hot)
// and scatters in CSR order, folding per-col dequant scale into ecv.y.
__launch_bounds__(256)
__global__ void k_fine2(const int2* __restrict__ binned, const int* __restrict__ bbase,
                        const float* __restrict__ scales, int2* __restrict__ ecv,
                        int* __restrict__ rs, int M, int E, int nbuck) {
    __shared__ int lcnt[BROWS];
    __shared__ int lcur[BROWS];
    const int b = blockIdx.x, t = threadIdx.x;
    const int r0 = b * BROWS;
    lcnt[t] = 0;
    const int start = __builtin_amdgcn_readfirstlane(bbase[b]);
    const int end   = __builtin_amdgcn_readfirstlane(bbase[b + 1]);
    __syncthreads();

    // sweep 1: count rows within bucket
    for (int i = start + t; i < end; i += 256)
        atomicAdd(&lcnt[binned[i].x >> 17], 1);
    __syncthreads();

    // block scan of 256 row counts
    int v = lcnt[t];
    lcur[t] = v;
    __syncthreads();
    for (int off = 1; off < 256; off <<= 1) {
        int x = (t >= off) ? lcur[t - off] : 0;
        __syncthreads();
        lcur[t] += x;
        __syncthreads();
    }
    int rowoff = start + (lcur[t] - v);    // global CSR offset of row r0+t
    if (r0 + t < M) rs[r0 + t] = rowoff;
    if (b == nbuck - 1 && t == 0) rs[M] = E;
    lcur[t] = rowoff;                      // own slot only; barrier below
    __syncthreads();

    // sweep 2: scatter into CSR order
    for (int i = start + t; i < end; i += 256) {
        int2 rec = binned[i];
        int r = rec.x >> 17;
        int col = rec.x & 0x1FFFF;
        int pos = atomicAdd(&lcur[r], 1);
        ecv[pos] = make_int2(col, __float_as_int(__int_as_float(rec.y) * scales[col]));
    }
}

// ---------------- fallback path kernels (use_binned == false) -----------------
__global__ void k_hist(const int* __restrict__ rows, int* __restrict__ counts, int E) {
    int i = (blockIdx.x * 256 + threadIdx.x) * 4;
    if (i + 4 <= E) {
        int4 r = *reinterpret_cast<const int4*>(&rows[i]);
        atomicAdd(&counts[r.x], 1);
        atomicAdd(&counts[r.y], 1);
        atomicAdd(&counts[r.z], 1);
        atomicAdd(&counts[r.w], 1);
    } else {
        for (int j = i; j < E; ++j) atomicAdd(&counts[rows[j]], 1);
    }
}

__global__ void k_scan1(const int* __restrict__ counts, int* __restrict__ rs,
                        int* __restrict__ bsum, int N) {
    int b = blockIdx.x, t = threadIdx.x;
    int base = b * 1024 + t * 4;
    int4 v = make_int4(0, 0, 0, 0);
    if (base + 4 <= N) v = *reinterpret_cast<const int4*>(&counts[base]);
    else {
        if (base + 0 < N) v.x = counts[base + 0];
        if (base + 1 < N) v.y = counts[base + 1];
        if (base + 2 < N) v.z = counts[base + 2];
        if (base + 3 < N) v.w = counts[base + 3];
    }
    int s0 = v.x, s1 = s0 + v.y, s2 = s1 + v.z, s3 = s2 + v.w;
    __shared__ int sh[256];
    sh[t] = s3; __syncthreads();
    for (int off = 1; off < 256; off <<= 1) {
        int x = (t >= off) ? sh[t - off] : 0;
        __syncthreads();
        sh[t] += x;
        __syncthreads();
    }
    int ex = sh[t] - s3;
    if (base + 0 < N) rs[base + 0] = ex;
    if (base + 1 < N) rs[base + 1] = ex + s0;
    if (base + 2 < N) rs[base + 2] = ex + s1;
    if (base + 3 < N) rs[base + 3] = ex + s2;
    if (t == 255) bsum[b] = sh[255];
}

__global__ void k_scan2(const int* __restrict__ bsum, int* __restrict__ boff, int nb) {
    int t = threadIdx.x;
    __shared__ int sh[256];
    int v = (t < nb) ? bsum[t] : 0;
    sh[t] = v; __syncthreads();
    for (int off = 1; off < 256; off <<= 1) {
        int x = (t >= off) ? sh[t - off] : 0;
        __syncthreads();
        sh[t] += x;
        __syncthreads();
    }
    if (t < nb) boff[t] = sh[t] - v;
}

__global__ void k_scan3(int* __restrict__ rs, int* __restrict__ cursor,
                        const int* __restrict__ boff, int N, int E) {
    int b = blockIdx.x, t = threadIdx.x;
    int base = b * 1024 + t * 4;
    int o = boff[b];
    #pragma unroll
    for (int j = 0; j < 4; ++j) {
        if (base + j < N) {
            int v = rs[base + j] + o;
            rs[base + j] = v;
            cursor[base + j] = v;
        }
    }
    if (b == 0 && t == 0) rs[N] = E;
}

__global__ void k_scatter(const int* __restrict__ rows, const int* __restrict__ cols,
                          const float* __restrict__ vals, const float* __restrict__ scales,
                          int* __restrict__ cursor, int2* __restrict__ ecv, int E) {
    int i = (blockIdx.x * 256 + threadIdx.x) * 4;
    if (i + 4 <= E) {
        int4 r = *reinterpret_cast<const int4*>(&rows[i]);
        int4 c = *reinterpret_cast<const int4*>(&cols[i]);
        float4 v = *reinterpret_cast<const float4*>(&vals[i]);
        int p0 = atomicAdd(&cursor[r.x], 1); ecv[p0] = make_int2(c.x, __float_as_int(v.x * scales[c.x]));
        int p1 = atomicAdd(&cursor[r.y], 1); ecv[p1] = make_int2(c.y, __float_as_int(v.y * scales[c.y]));
        int p2 = atomicAdd(&cursor[r.z], 1); ecv[p2] = make_int2(c.z, __float_as_int(v.z * scales[c.z]));
        int p3 = atomicAdd(&cursor[r.w], 1); ecv[p3] = make_int2(c.w, __float_as_int(v.w * scales[c.w]));
    } else {
        for (int j = i; j < E; ++j) {
            int p = atomicAdd(&cursor[rows[j]], 1);
            ecv[p] = make_int2(cols[j], __float_as_int(vals[j] * scales[cols[j]]));
        }
    }
}

// ---------------- CSR aggregation + fused epilogue (INT8 gather) --------------
__launch_bounds__(256)
__global__ void k_agg(const signed char* __restrict__ xq,
                      const float* __restrict__ scales,
                      const int2* __restrict__ ecv,
                      const int* __restrict__ rs,
                      const float* __restrict__ skipw,
                      const float* __restrict__ bias,
                      float* __restrict__ out, int M) {
    const int wave = threadIdx.x >> 6, lane = threadIdx.x & 63;
    const int node = blockIdx.x * 4 + wave;
    if (node >= M) return;
    const int s = __builtin_amdgcn_readfirstlane(rs[node]);
    const int e = __builtin_amdgcn_readfirstlane(rs[node + 1]);
    const int d4 = lane * 4;

    float a0 = 0.f, a1 = 0.f, a2 = 0.f, a3 = 0.f;
    int p = s;
    constexpr int U = 8;
    for (; p + U <= e; p += U) {
        int   cs[U];
        float vs[U];
        #pragma unroll
        for (int u = 0; u < U; ++u) {
            int2 c = ecv[p + u];           // wave-uniform address -> L1 broadcast
            cs[u] = c.x; vs[u] = __int_as_float(c.y);
        }
        int g[U];
        #pragma unroll
        for (int u = 0; u < U; ++u)
            g[u] = *reinterpret_cast<const int*>(&xq[(size_t)cs[u] * OUT_DIM + d4]);
        #pragma unroll
        for (int u = 0; u < U; ++u) {
            a0 += vs[u] * (float)(signed char)(g[u]);
            a1 += vs[u] * (float)(signed char)(g[u] >> 8);
            a2 += vs[u] * (float)(signed char)(g[u] >> 16);
            a3 += vs[u] * (float)(g[u] >> 24);
        }
    }
    for (; p < e; ++p) {
        int2 c = ecv[p];
        float v = __int_as_float(c.y);
        int g = *reinterpret_cast<const int*>(&xq[(size_t)c.x * OUT_DIM + d4]);
        a0 += v * (float)(signed char)(g);
        a1 += v * (float)(signed char)(g >> 8);
        a2 += v * (float)(signed char)(g >> 16);
        a3 += v * (float)(g >> 24);
    }

    // skip path: own row int8 + own scale
    int w = *reinterpret_cast<const int*>(&xq[(size_t)node * OUT_DIM + d4]);
    float sc = scales[node];
    float x0 = (float)(signed char)(w)        * sc;
    float x1 = (float)(signed char)(w >> 8)   * sc;
    float x2 = (float)(signed char)(w >> 16)  * sc;
    float x3 = (float)(w >> 24)               * sc;

    float4 sw = *reinterpret_cast<const float4*>(&skipw[d4]);
    float4 bi = *reinterpret_cast<const float4*>(&bias[d4]);
    float4 r;
    r.x = selu(a0 + x0 * sw.x + bi.x);
    r.y = selu(a1 + x1 * sw.y + bi.y);
    r.z = selu(a2 + x2 * sw.z + bi.z);
    r.w = selu(a3 + x3 * sw.w + bi.w);
    *reinterpret_cast<float4*>(&out[(size_t)node * OUT_DIM + d4]) = r;
}

extern "C" void kernel_launch(void* const* d_in, const int* in_sizes, int n_in,
                              void* d_out, int out_size, void* d_ws, size_t ws_size,
                              hipStream_t stream) {
    const float* features = (const float*)d_in[0];
    const int*   adj_rows = (const int*)d_in[1];
    const int*   adj_cols = (const int*)d_in[2];
    const float* adj_vals = (const float*)d_in[3];
    const float* Wk       = (const float*)d_in[4];
    const float* bias     = (const float*)d_in[5];
    const float* skipw    = (const float*)d_in[6];
    float* out = (float*)d_out;

    const int M = in_sizes[0] / IN_DIM;     // 100000
    const int E = in_sizes[1];              // 3200000

    char* w = (char*)d_ws;
    size_t off = 0;
    auto carve = [&](size_t bytes) -> void* {
        void* p = w + off;
        off = (off + bytes + 255) & ~(size_t)255;
        return p;
    };
    signed char* xq = (signed char*)carve((size_t)M * OUT_DIM);             // 25.6 MB
    float* scales   = (float*)carve((size_t)M * 4);                         // 0.4 MB
    unsigned short* Wt = (unsigned short*)carve((size_t)IN_DIM * OUT_DIM * 2);
    int*  counts = (int*)carve((size_t)M * 4);
    int*  rs     = (int*)carve((size_t)(M + 1) * 4);
    int*  cursor = (int*)carve((size_t)M * 4);
    int*  bsum   = (int*)carve(256 * 4);
    int*  boff   = (int*)carve(256 * 4);
    int*  bcnt   = (int*)carve((NBUCK_MAX + 1) * 4);
    int*  bbase  = (int*)carve((NBUCK_MAX + 1) * 4);
    int*  bcur   = (int*)carve((NBUCK_MAX + 1) * 4);
    int2* ecv    = (int2*)carve((size_t)E * 8);                             // 25.6 MB
    int2* binned = (int2*)carve((size_t)E * 8);                             // 25.6 MB
    const int nbuck = (M + BROWS - 1) / BROWS;
    const bool use_binned = (off <= ws_size) && (nbuck <= NBUCK_MAX) && (M <= (1 << 17));

    k_convW<<<(IN_DIM * OUT_DIM + 255) / 256, 256, 0, stream>>>(Wk, Wt);
    k_gemm<<<(M + 127) / 128, 512, 0, stream>>>(features, Wt, xq, scales, M);

    if (use_binned) {
        hipMemsetAsync(bcnt, 0, (NBUCK_MAX + 1) * 4, stream);
        k_bhist<<<(E + 8191) / 8192, 512, 0, stream>>>(adj_rows, bcnt, E);
        k_bscan<<<1, NBUCK_MAX, 0, stream>>>(bcnt, bbase, bcur, nbuck, E);
        k_bin<<<(E + 8191) / 8192, 512, 0, stream>>>(adj_rows, adj_cols, adj_vals, bcur, binned, E);
        k_fine2<<<nbuck, 256, 0, stream>>>(binned, bbase, scales, ecv, rs, M, E, nbuck);
    } else {
        hipMemsetAsync(counts, 0, (size_t)M * 4, stream);
        k_hist<<<(E / 4 + 255) / 256, 256, 0, stream>>>(adj_rows, counts, E);
        int nb = (M + 1023) / 1024;
        k_scan1<<<nb, 256, 0, stream>>>(counts, rs, bsum, M);
        k_scan2<<<1, 256, 0, stream>>>(bsum, boff, nb);
        k_scan3<<<nb, 256, 0, stream>>>(rs, cursor, boff, M, E);
        k_scatter<<<(E / 4 + 255) / 256, 256, 0, stream>>>(adj_rows, adj_cols, adj_vals, scales, cursor, ecv, E);
    }

    k_agg<<<(M + 3) / 4, 256, 0, stream>>>(xq, scales, ecv, rs, skipw, bias, out, M);
}